// Round 2
// baseline (11495.493 us; speedup 1.0000x reference)
//
#include <hip/hip_runtime.h>
#include <hip/hip_bf16.h>

// MVAE fused pipeline, round 2: dtype-self-detecting (fp32 vs bf16 inputs).
// ws layout: [0..63] flag int (1 = bf16, 0 = fp32), [64..] gather table:
//   per (n,mod): 16 u16 = [mu0..5, lv0..5, pad*4] (32B, one L2-line pair).

#define LL 6
#define HH 64
#define VV 51
#define KK 64

typedef unsigned short u16;
typedef __hip_bfloat16 bf16;

__device__ __forceinline__ float blo(unsigned int x) {
    union { unsigned int i; float f; } v; v.i = x << 16; return v.f;
}
__device__ __forceinline__ float bhi(unsigned int x) {
    union { unsigned int i; float f; } v; v.i = x & 0xffff0000u; return v.f;
}
__device__ __forceinline__ u16 f2b16(float f) {
    __hip_bfloat16 h = __float2bfloat16(f);
    u16 u; __builtin_memcpy(&u, &h, 2); return u;
}
__device__ __forceinline__ float swishf(float x) {
    return x / (1.0f + __expf(-x));
}
// dtype-flexible load/store (isb is wave-uniform -> scalar branch)
__device__ __forceinline__ float ldv(const void* p, size_t i, int isb) {
    return isb ? __bfloat162float(((const bf16*)p)[i]) : ((const float*)p)[i];
}
__device__ __forceinline__ void stv(void* p, size_t i, int isb, float v) {
    if (isb) ((bf16*)p)[i] = __float2bfloat16(v);
    else     ((float*)p)[i] = v;
}

// ---------------- Kernel 0: dtype detect ----------------
__global__ void k_detect(const unsigned int* __restrict__ obsw, int* __restrict__ flag) {
    // For bf16 data, bits 14..7 of each 32-bit word are the low element's
    // exponent (sane range for N(0,1) values). For fp32 data they are
    // mantissa bits (uniform). Vote across 64 lanes.
    unsigned int w = obsw[threadIdx.x];
    unsigned int e = (w >> 7) & 0xFFu;
    bool sane = (e >= 0x70u && e <= 0x87u);
    unsigned long long m = __ballot(sane);
    if (threadIdx.x == 0) flag[0] = (__popcll(m) >= 40) ? 1 : 0;
}

// ---------------- Kernel A: encoder ----------------
__global__ __launch_bounds__(256) void k_encode(
    const void* __restrict__ obs,
    const void* __restrict__ We1, const void* __restrict__ be1,
    const void* __restrict__ We2, const void* __restrict__ be2,
    const void* __restrict__ We3, const void* __restrict__ be3,
    const int* __restrict__ flag, u16* __restrict__ gt, int N)
{
    __shared__ float sW1[2 * 64];
    __shared__ float sb1[64];
    __shared__ float sW2[64 * 64];
    __shared__ float sb2[64];
    __shared__ float sW3[64 * 24];
    __shared__ float sb3[24];
    const int isb = flag[0];
    const int tid = threadIdx.x;
    for (int i = tid; i < 128; i += 256) sW1[i] = ldv(We1, i, isb);
    if (tid < 64) sb1[tid] = ldv(be1, tid, isb);
    for (int i = tid; i < 4096; i += 256) sW2[i] = ldv(We2, i, isb);
    if (tid < 64) sb2[tid] = ldv(be2, tid, isb);
    for (int i = tid; i < 1536; i += 256) sW3[i] = ldv(We3, i, isb);
    if (tid < 24) sb3[tid] = ldv(be3, tid, isb);
    __syncthreads();

    const int n = blockIdx.x * 256 + tid;
    if (n >= N) return;

    const float o0 = ldv(obs, 2 * (size_t)n, isb);
    const float o1 = ldv(obs, 2 * (size_t)n + 1, isb);

    float h1[64];
#pragma unroll
    for (int j = 0; j < 64; ++j)
        h1[j] = swishf(o0 * sW1[j] + o1 * sW1[64 + j] + sb1[j]);

    float h2[64];
#pragma unroll
    for (int j = 0; j < 64; ++j) h2[j] = sb2[j];
#pragma unroll
    for (int i = 0; i < 64; ++i) {
        const float a = h1[i];
        const float4* row = (const float4*)(sW2 + i * 64);
#pragma unroll
        for (int j4 = 0; j4 < 16; ++j4) {
            float4 w = row[j4];
            h2[4 * j4 + 0] += a * w.x; h2[4 * j4 + 1] += a * w.y;
            h2[4 * j4 + 2] += a * w.z; h2[4 * j4 + 3] += a * w.w;
        }
    }
#pragma unroll
    for (int j = 0; j < 64; ++j) h2[j] = swishf(h2[j]);

    float o[24];
#pragma unroll
    for (int j = 0; j < 24; ++j) o[j] = sb3[j];
#pragma unroll
    for (int i = 0; i < 64; ++i) {
        const float a = h2[i];
        const float4* row = (const float4*)(sW3 + i * 24);
#pragma unroll
        for (int j4 = 0; j4 < 6; ++j4) {
            float4 w = row[j4];
            o[4 * j4 + 0] += a * w.x; o[4 * j4 + 1] += a * w.y;
            o[4 * j4 + 2] += a * w.z; o[4 * j4 + 3] += a * w.w;
        }
    }

    u16* g = gt + (size_t)n * 32;
#pragma unroll
    for (int mod = 0; mod < 2; ++mod) {
        float e[16];
#pragma unroll
        for (int l = 0; l < 6; ++l) {
            e[l]     = o[mod * 6 + l];       // mu
            e[6 + l] = o[12 + mod * 6 + l];  // logvar
        }
        e[12] = 0.f; e[13] = 0.f; e[14] = 0.f; e[15] = 0.f;
        unsigned int pk[8];
#pragma unroll
        for (int i = 0; i < 8; ++i)
            pk[i] = (unsigned int)f2b16(e[2 * i]) | ((unsigned int)f2b16(e[2 * i + 1]) << 16);
        *(int4*)(g + mod * 16)     = make_int4(pk[0], pk[1], pk[2], pk[3]);
        *(int4*)(g + mod * 16 + 8) = make_int4(pk[4], pk[5], pk[6], pk[7]);
    }
}

// ---------------- Kernel B: PoE + decode + outputs ----------------
__global__ __launch_bounds__(256) void k_poe_decode(
    const void* __restrict__ p,
    const void* __restrict__ eps_skip, const void* __restrict__ eps_poe,
    const int* __restrict__ nbs, const int* __restrict__ nbo,
    const void* __restrict__ Wd1, const void* __restrict__ bd1,
    const void* __restrict__ Wd2, const void* __restrict__ bd2,
    const void* __restrict__ Wd3, const void* __restrict__ bd3,
    const int* __restrict__ flag, const u16* __restrict__ gt,
    void* __restrict__ out, int N)
{
    __shared__ float sW1[6 * 64];
    __shared__ float sb1[64];
    __shared__ float sW2[64 * 64];
    __shared__ float sb2[64];
    __shared__ float sW3[64 * 52];   // rows padded 51->52
    __shared__ float sb3[52];
    const int isb = flag[0];
    const int tid = threadIdx.x;
    for (int i = tid; i < 384; i += 256) sW1[i] = ldv(Wd1, i, isb);
    if (tid < 64) sb1[tid] = ldv(bd1, tid, isb);
    for (int i = tid; i < 4096; i += 256) sW2[i] = ldv(Wd2, i, isb);
    if (tid < 64) sb2[tid] = ldv(bd2, tid, isb);
    for (int t = tid; t < 64 * 52; t += 256) {
        int i = t / 52, v = t - i * 52;
        sW3[t] = (v < 51) ? ldv(Wd3, i * 51 + v, isb) : 0.f;
    }
    if (tid < 52) sb3[tid] = (tid < 51) ? ldv(bd3, tid, isb) : 0.f;
    __syncthreads();

    const int idx = blockIdx.x * 256 + tid;   // over 2N (n,mod) pairs
    const int n = idx >> 1;
    const int mod = idx & 1;
    if (n >= N) return;

    const bool skip = ldv(p, n, isb) < 0.5f;

    const u16* g = gt + (size_t)n * 32 + mod * 16;
    int4 sa = *(const int4*)g;
    int2 sbv = *(const int2*)(g + 8);
    float mu[6], lv[6];
    mu[0] = blo(sa.x); mu[1] = bhi(sa.x); mu[2] = blo(sa.y);
    mu[3] = bhi(sa.y); mu[4] = blo(sa.z); mu[5] = bhi(sa.z);
    lv[0] = blo(sa.w); lv[1] = bhi(sa.w); lv[2] = blo(sbv.x);
    lv[3] = bhi(sbv.x); lv[4] = blo(sbv.y); lv[5] = bhi(sbv.y);

    float z[6], outmu[6], outlv[6];

    if (!skip) {
        float sT[6], sM[6];
        const float priorT = 1.0f / (1.0f + 1e-8f);
#pragma unroll
        for (int l = 0; l < 6; ++l) {
            float T = 1.0f / (__expf(lv[l]) + 1e-8f);
            sT[l] = priorT + T;
            sM[l] = mu[l] * T;
        }
        const int4* ps = (const int4*)(nbs + (size_t)idx * 64);
        const int4* po = (const int4*)(nbo + (size_t)idx * 64);
#pragma unroll 4
        for (int k4 = 0; k4 < 16; ++k4) {
            int4 s4 = ps[k4];
            int4 o4 = po[k4];
            int ss[4] = { s4.x, s4.y, s4.z, s4.w };
            int oo[4] = { o4.x, o4.y, o4.z, o4.w };
#pragma unroll
            for (int u = 0; u < 4; ++u) {
                int sidx = ss[u]; if ((unsigned)sidx >= (unsigned)N) sidx = 0;  // insurance
                int oidx = oo[u] & 1;
                const u16* e = gt + (size_t)sidx * 32 + oidx * 16;
                int4 a = *(const int4*)e;
                int2 b = *(const int2*)(e + 8);
                float m0 = blo(a.x), m1 = bhi(a.x), m2 = blo(a.y);
                float m3 = bhi(a.y), m4 = blo(a.z), m5 = bhi(a.z);
                float v0 = blo(a.w), v1 = bhi(a.w), v2 = blo(b.x);
                float v3 = bhi(b.x), v4 = blo(b.y), v5 = bhi(b.y);
                float T0 = 1.0f / (__expf(v0) + 1e-8f); sT[0] += T0; sM[0] += m0 * T0;
                float T1 = 1.0f / (__expf(v1) + 1e-8f); sT[1] += T1; sM[1] += m1 * T1;
                float T2 = 1.0f / (__expf(v2) + 1e-8f); sT[2] += T2; sM[2] += m2 * T2;
                float T3 = 1.0f / (__expf(v3) + 1e-8f); sT[3] += T3; sM[3] += m3 * T3;
                float T4 = 1.0f / (__expf(v4) + 1e-8f); sT[4] += T4; sM[4] += m4 * T4;
                float T5 = 1.0f / (__expf(v5) + 1e-8f); sT[5] += T5; sM[5] += m5 * T5;
            }
        }
#pragma unroll
        for (int l = 0; l < 6; ++l) {
            float pm = sM[l] / sT[l];
            outmu[l] = pm;
            outlv[l] = -__logf(sT[l]);
            z[l] = pm + ldv(eps_poe, (size_t)idx * 6 + l, isb) * rsqrtf(sT[l]);
        }
    } else {
#pragma unroll
        for (int l = 0; l < 6; ++l) {
            outmu[l] = mu[l];
            outlv[l] = lv[l];
            z[l] = mu[l] + ldv(eps_skip, (size_t)idx * 6 + l, isb) * __expf(0.5f * lv[l]);
        }
    }

    {
        const size_t om = (size_t)N * 102 + (size_t)idx * 6;
        const size_t ol = (size_t)N * 114 + (size_t)idx * 6;
#pragma unroll
        for (int l = 0; l < 6; ++l) {
            stv(out, om + l, isb, outmu[l]);
            stv(out, ol + l, isb, outlv[l]);
        }
    }

    // decode(z): 6 -> 64 -> 64 -> 51
    float h1[64];
#pragma unroll
    for (int j = 0; j < 64; ++j) h1[j] = sb1[j];
#pragma unroll
    for (int l = 0; l < 6; ++l) {
        const float a = z[l];
        const float4* row = (const float4*)(sW1 + l * 64);
#pragma unroll
        for (int j4 = 0; j4 < 16; ++j4) {
            float4 w = row[j4];
            h1[4 * j4 + 0] += a * w.x; h1[4 * j4 + 1] += a * w.y;
            h1[4 * j4 + 2] += a * w.z; h1[4 * j4 + 3] += a * w.w;
        }
    }
#pragma unroll
    for (int j = 0; j < 64; ++j) h1[j] = swishf(h1[j]);

    float h2[64];
#pragma unroll
    for (int j = 0; j < 64; ++j) h2[j] = sb2[j];
#pragma unroll
    for (int i = 0; i < 64; ++i) {
        const float a = h1[i];
        const float4* row = (const float4*)(sW2 + i * 64);
#pragma unroll
        for (int j4 = 0; j4 < 16; ++j4) {
            float4 w = row[j4];
            h2[4 * j4 + 0] += a * w.x; h2[4 * j4 + 1] += a * w.y;
            h2[4 * j4 + 2] += a * w.z; h2[4 * j4 + 3] += a * w.w;
        }
    }
#pragma unroll
    for (int j = 0; j < 64; ++j) h2[j] = swishf(h2[j]);

    float r[52];
#pragma unroll
    for (int j = 0; j < 52; ++j) r[j] = sb3[j];
#pragma unroll
    for (int i = 0; i < 64; ++i) {
        const float a = h2[i];
        const float4* row = (const float4*)(sW3 + i * 52);
#pragma unroll
        for (int j4 = 0; j4 < 13; ++j4) {
            float4 w = row[j4];
            r[4 * j4 + 0] += a * w.x; r[4 * j4 + 1] += a * w.y;
            r[4 * j4 + 2] += a * w.z; r[4 * j4 + 3] += a * w.w;
        }
    }

    const size_t ro = (size_t)n * 102 + (size_t)mod * 51;
#pragma unroll
    for (int v = 0; v < 51; ++v) stv(out, ro + v, isb, r[v]);
}

extern "C" void kernel_launch(void* const* d_in, const int* in_sizes, int n_in,
                              void* d_out, int out_size, void* d_ws, size_t ws_size,
                              hipStream_t stream) {
    const int N = in_sizes[0] / 2;
    const void* obs      = d_in[0];
    const void* p        = d_in[1];
    const void* eps_skip = d_in[2];
    const void* eps_poe  = d_in[3];
    const int*  nbs      = (const int*)d_in[4];
    const int*  nbo      = (const int*)d_in[5];

    int* flag = (int*)d_ws;                 // 64-byte flag region
    u16* gt   = (u16*)d_ws + 32;            // gather table, N*64 bytes

    dim3 blk(256);
    dim3 grdA((N + 255) / 256);
    dim3 grdB((2 * N + 255) / 256);
    hipLaunchKernelGGL(k_detect, dim3(1), dim3(64), 0, stream,
                       (const unsigned int*)obs, flag);
    hipLaunchKernelGGL(k_encode, grdA, blk, 0, stream,
                       obs, d_in[6], d_in[7], d_in[8], d_in[9], d_in[10], d_in[11],
                       flag, gt, N);
    hipLaunchKernelGGL(k_poe_decode, grdB, blk, 0, stream,
                       p, eps_skip, eps_poe, nbs, nbo,
                       d_in[12], d_in[13], d_in[14], d_in[15], d_in[16], d_in[17],
                       flag, gt, (void*)d_out, N);
}

// Round 3
// 1260.432 us; speedup vs baseline: 9.1203x; 9.1203x over previous
//
#include <hip/hip_runtime.h>
#include <hip/hip_bf16.h>

// MVAE fused pipeline, round 3: spill elimination.
// Round-2 post-mortem: VGPR=256 + 21 GB of scratch traffic (WRITE_SIZE 100x
// program output) = register arrays spilled. Fix: h1 lives in LDS (bf16,
// per-thread column), layer-2 output chunked (acc[16]) and streamed straight
// into the layer-3 accumulator, so no >64-float register array exists.
// Gather/PoE phase unchanged from round 2 (proven correct).
// ws layout: [0..63B] dtype flag int, [64B..] gather table (n,mod):
//   16 u16 = [mu0..5, lv0..5, pad*4] (32B).

typedef unsigned short u16;
typedef __hip_bfloat16 bf16;

__device__ __forceinline__ float blo(unsigned int x) {
    union { unsigned int i; float f; } v; v.i = x << 16; return v.f;
}
__device__ __forceinline__ float bhi(unsigned int x) {
    union { unsigned int i; float f; } v; v.i = x & 0xffff0000u; return v.f;
}
__device__ __forceinline__ u16 f2b16(float f) {
    __hip_bfloat16 h = __float2bfloat16(f);
    u16 u; __builtin_memcpy(&u, &h, 2); return u;
}
__device__ __forceinline__ float b2f(u16 u) {
    union { unsigned int i; float f; } v; v.i = ((unsigned int)u) << 16; return v.f;
}
__device__ __forceinline__ float swishf(float x) {
    return x / (1.0f + __expf(-x));
}
// dtype-flexible load/store (isb is wave-uniform -> scalar branch)
__device__ __forceinline__ float ldv(const void* p, size_t i, int isb) {
    return isb ? __bfloat162float(((const bf16*)p)[i]) : ((const float*)p)[i];
}
__device__ __forceinline__ void stv(void* p, size_t i, int isb, float v) {
    if (isb) ((bf16*)p)[i] = __float2bfloat16(v);
    else     ((float*)p)[i] = v;
}

// ---------------- Kernel 0: dtype detect ----------------
__global__ void k_detect(const unsigned int* __restrict__ obsw, int* __restrict__ flag) {
    unsigned int w = obsw[threadIdx.x];
    unsigned int e = (w >> 7) & 0xFFu;
    bool sane = (e >= 0x70u && e <= 0x87u);
    unsigned long long m = __ballot(sane);
    if (threadIdx.x == 0) flag[0] = (__popcll(m) >= 40) ? 1 : 0;
}

// ---------------- Kernel A: encoder ----------------
__global__ __launch_bounds__(256) void k_encode(
    const void* __restrict__ obs,
    const void* __restrict__ We1, const void* __restrict__ be1,
    const void* __restrict__ We2, const void* __restrict__ be2,
    const void* __restrict__ We3, const void* __restrict__ be3,
    const int* __restrict__ flag, u16* __restrict__ gt, int N)
{
    __shared__ float sW1[2 * 64];
    __shared__ float sb1[64];
    __shared__ float sW2[64 * 64];
    __shared__ float sb2[64];
    __shared__ float sW3[64 * 24];
    __shared__ float sb3[24];
    __shared__ u16 sh1[64 * 256];   // h1 bf16, [feature][tid] column layout
    const int isb = flag[0];
    const int tid = threadIdx.x;
    for (int i = tid; i < 128; i += 256) sW1[i] = ldv(We1, i, isb);
    if (tid < 64) sb1[tid] = ldv(be1, tid, isb);
    for (int i = tid; i < 4096; i += 256) sW2[i] = ldv(We2, i, isb);
    if (tid < 64) sb2[tid] = ldv(be2, tid, isb);
    for (int i = tid; i < 1536; i += 256) sW3[i] = ldv(We3, i, isb);
    if (tid < 24) sb3[tid] = ldv(be3, tid, isb);
    __syncthreads();

    const int n = blockIdx.x * 256 + tid;
    if (n >= N) return;

    const float o0 = ldv(obs, 2 * (size_t)n, isb);
    const float o1 = ldv(obs, 2 * (size_t)n + 1, isb);

    // L1: 2 -> 64, straight to LDS (own column only; no barrier needed)
#pragma unroll 8
    for (int j = 0; j < 64; ++j) {
        float v = swishf(o0 * sW1[j] + o1 * sW1[64 + j] + sb1[j]);
        sh1[j * 256 + tid] = f2b16(v);
    }

    // L2 (64->64, chunks of 16) streamed into L3 accumulator o[24]
    float o[24];
#pragma unroll
    for (int v = 0; v < 24; ++v) o[v] = sb3[v];

    for (int jc = 0; jc < 4; ++jc) {
        float acc[16];
#pragma unroll
        for (int k = 0; k < 16; ++k) acc[k] = sb2[jc * 16 + k];
        for (int i = 0; i < 64; ++i) {
            const float a = b2f(sh1[i * 256 + tid]);
            const float4* w4 = (const float4*)(sW2 + i * 64 + jc * 16);
#pragma unroll
            for (int k4 = 0; k4 < 4; ++k4) {
                float4 w = w4[k4];
                acc[4 * k4 + 0] += a * w.x; acc[4 * k4 + 1] += a * w.y;
                acc[4 * k4 + 2] += a * w.z; acc[4 * k4 + 3] += a * w.w;
            }
        }
#pragma unroll
        for (int k = 0; k < 16; ++k) {
            const float a = swishf(acc[k]);
            const float4* w4 = (const float4*)(sW3 + (jc * 16 + k) * 24);
#pragma unroll
            for (int v4 = 0; v4 < 6; ++v4) {
                float4 w = w4[v4];
                o[4 * v4 + 0] += a * w.x; o[4 * v4 + 1] += a * w.y;
                o[4 * v4 + 2] += a * w.z; o[4 * v4 + 3] += a * w.w;
            }
        }
    }

    // pack gather-table entries (same format as round 2)
    u16* g = gt + (size_t)n * 32;
#pragma unroll
    for (int mod = 0; mod < 2; ++mod) {
        float e[16];
#pragma unroll
        for (int l = 0; l < 6; ++l) {
            e[l]     = o[mod * 6 + l];       // mu
            e[6 + l] = o[12 + mod * 6 + l];  // logvar
        }
        e[12] = 0.f; e[13] = 0.f; e[14] = 0.f; e[15] = 0.f;
        unsigned int pk[8];
#pragma unroll
        for (int i = 0; i < 8; ++i)
            pk[i] = (unsigned int)f2b16(e[2 * i]) | ((unsigned int)f2b16(e[2 * i + 1]) << 16);
        *(int4*)(g + mod * 16)     = make_int4(pk[0], pk[1], pk[2], pk[3]);
        *(int4*)(g + mod * 16 + 8) = make_int4(pk[4], pk[5], pk[6], pk[7]);
    }
}

// ---------------- Kernel B: PoE + decode + outputs ----------------
__global__ __launch_bounds__(256) void k_poe_decode(
    const void* __restrict__ p,
    const void* __restrict__ eps_skip, const void* __restrict__ eps_poe,
    const int* __restrict__ nbs, const int* __restrict__ nbo,
    const void* __restrict__ Wd1, const void* __restrict__ bd1,
    const void* __restrict__ Wd2, const void* __restrict__ bd2,
    const void* __restrict__ Wd3, const void* __restrict__ bd3,
    const int* __restrict__ flag, const u16* __restrict__ gt,
    void* __restrict__ out, int N)
{
    __shared__ float sW1[6 * 64];
    __shared__ float sb1[64];
    __shared__ float sW2[64 * 64];
    __shared__ float sb2[64];
    __shared__ float sW3[64 * 52];   // rows padded 51->52
    __shared__ float sb3[52];
    __shared__ u16 sh1[64 * 256];    // h1 bf16, [feature][tid]
    const int isb = flag[0];
    const int tid = threadIdx.x;
    for (int i = tid; i < 384; i += 256) sW1[i] = ldv(Wd1, i, isb);
    if (tid < 64) sb1[tid] = ldv(bd1, tid, isb);
    for (int i = tid; i < 4096; i += 256) sW2[i] = ldv(Wd2, i, isb);
    if (tid < 64) sb2[tid] = ldv(bd2, tid, isb);
    for (int t = tid; t < 64 * 52; t += 256) {
        int i = t / 52, v = t - i * 52;
        sW3[t] = (v < 51) ? ldv(Wd3, i * 51 + v, isb) : 0.f;
    }
    if (tid < 52) sb3[tid] = (tid < 51) ? ldv(bd3, tid, isb) : 0.f;
    __syncthreads();

    const int idx = blockIdx.x * 256 + tid;   // over 2N (n,mod) pairs
    const int n = idx >> 1;
    const int mod = idx & 1;
    if (n >= N) return;

    const bool skip = ldv(p, n, isb) < 0.5f;

    // ---- Phase A: PoE / reparameterize (unchanged from round 2) ----
    const u16* g = gt + (size_t)n * 32 + mod * 16;
    int4 sa = *(const int4*)g;
    int2 sbv = *(const int2*)(g + 8);
    float mu[6], lv[6];
    mu[0] = blo(sa.x); mu[1] = bhi(sa.x); mu[2] = blo(sa.y);
    mu[3] = bhi(sa.y); mu[4] = blo(sa.z); mu[5] = bhi(sa.z);
    lv[0] = blo(sa.w); lv[1] = bhi(sa.w); lv[2] = blo(sbv.x);
    lv[3] = bhi(sbv.x); lv[4] = blo(sbv.y); lv[5] = bhi(sbv.y);

    float z[6], outmu[6], outlv[6];

    if (!skip) {
        float sT[6], sM[6];
        const float priorT = 1.0f / (1.0f + 1e-8f);
#pragma unroll
        for (int l = 0; l < 6; ++l) {
            float T = 1.0f / (__expf(lv[l]) + 1e-8f);
            sT[l] = priorT + T;
            sM[l] = mu[l] * T;
        }
        const int4* ps = (const int4*)(nbs + (size_t)idx * 64);
        const int4* po = (const int4*)(nbo + (size_t)idx * 64);
#pragma unroll 4
        for (int k4 = 0; k4 < 16; ++k4) {
            int4 s4 = ps[k4];
            int4 o4 = po[k4];
            int ss[4] = { s4.x, s4.y, s4.z, s4.w };
            int oo[4] = { o4.x, o4.y, o4.z, o4.w };
#pragma unroll
            for (int u = 0; u < 4; ++u) {
                int sidx = ss[u]; if ((unsigned)sidx >= (unsigned)N) sidx = 0;
                int oidx = oo[u] & 1;
                const u16* e = gt + (size_t)sidx * 32 + oidx * 16;
                int4 a = *(const int4*)e;
                int2 b = *(const int2*)(e + 8);
                float m0 = blo(a.x), m1 = bhi(a.x), m2 = blo(a.y);
                float m3 = bhi(a.y), m4 = blo(a.z), m5 = bhi(a.z);
                float v0 = blo(a.w), v1 = bhi(a.w), v2 = blo(b.x);
                float v3 = bhi(b.x), v4 = blo(b.y), v5 = bhi(b.y);
                float T0 = 1.0f / (__expf(v0) + 1e-8f); sT[0] += T0; sM[0] += m0 * T0;
                float T1 = 1.0f / (__expf(v1) + 1e-8f); sT[1] += T1; sM[1] += m1 * T1;
                float T2 = 1.0f / (__expf(v2) + 1e-8f); sT[2] += T2; sM[2] += m2 * T2;
                float T3 = 1.0f / (__expf(v3) + 1e-8f); sT[3] += T3; sM[3] += m3 * T3;
                float T4 = 1.0f / (__expf(v4) + 1e-8f); sT[4] += T4; sM[4] += m4 * T4;
                float T5 = 1.0f / (__expf(v5) + 1e-8f); sT[5] += T5; sM[5] += m5 * T5;
            }
        }
#pragma unroll
        for (int l = 0; l < 6; ++l) {
            float pm = sM[l] / sT[l];
            outmu[l] = pm;
            outlv[l] = -__logf(sT[l]);
            z[l] = pm + ldv(eps_poe, (size_t)idx * 6 + l, isb) * rsqrtf(sT[l]);
        }
    } else {
#pragma unroll
        for (int l = 0; l < 6; ++l) {
            outmu[l] = mu[l];
            outlv[l] = lv[l];
            z[l] = mu[l] + ldv(eps_skip, (size_t)idx * 6 + l, isb) * __expf(0.5f * lv[l]);
        }
    }

    {
        const size_t om = (size_t)N * 102 + (size_t)idx * 6;
        const size_t ol = (size_t)N * 114 + (size_t)idx * 6;
#pragma unroll
        for (int l = 0; l < 6; ++l) {
            stv(out, om + l, isb, outmu[l]);
            stv(out, ol + l, isb, outlv[l]);
        }
    }

    // ---- Phase B: decode(z) 6 -> 64 -> 64 -> 51, spill-free ----
    // L1: z -> h1 (LDS bf16, own column)
#pragma unroll 4
    for (int j4 = 0; j4 < 16; ++j4) {
        float a0 = sb1[4 * j4 + 0], a1 = sb1[4 * j4 + 1];
        float a2 = sb1[4 * j4 + 2], a3 = sb1[4 * j4 + 3];
#pragma unroll
        for (int l = 0; l < 6; ++l) {
            float4 w = ((const float4*)(sW1 + l * 64))[j4];
            a0 += z[l] * w.x; a1 += z[l] * w.y;
            a2 += z[l] * w.z; a3 += z[l] * w.w;
        }
        sh1[(4 * j4 + 0) * 256 + tid] = f2b16(swishf(a0));
        sh1[(4 * j4 + 1) * 256 + tid] = f2b16(swishf(a1));
        sh1[(4 * j4 + 2) * 256 + tid] = f2b16(swishf(a2));
        sh1[(4 * j4 + 3) * 256 + tid] = f2b16(swishf(a3));
    }

    // L2 (chunks of 16) streamed into L3 accumulator r[52]
    float r[52];
#pragma unroll
    for (int v = 0; v < 52; ++v) r[v] = sb3[v];

    for (int jc = 0; jc < 4; ++jc) {
        float acc[16];
#pragma unroll
        for (int k = 0; k < 16; ++k) acc[k] = sb2[jc * 16 + k];
        for (int i = 0; i < 64; ++i) {
            const float a = b2f(sh1[i * 256 + tid]);
            const float4* w4 = (const float4*)(sW2 + i * 64 + jc * 16);
#pragma unroll
            for (int k4 = 0; k4 < 4; ++k4) {
                float4 w = w4[k4];
                acc[4 * k4 + 0] += a * w.x; acc[4 * k4 + 1] += a * w.y;
                acc[4 * k4 + 2] += a * w.z; acc[4 * k4 + 3] += a * w.w;
            }
        }
#pragma unroll
        for (int k = 0; k < 16; ++k) {
            const float a = swishf(acc[k]);
            const float4* w4 = (const float4*)(sW3 + (jc * 16 + k) * 52);
#pragma unroll
            for (int v4 = 0; v4 < 13; ++v4) {
                float4 w = w4[v4];
                r[4 * v4 + 0] += a * w.x; r[4 * v4 + 1] += a * w.y;
                r[4 * v4 + 2] += a * w.z; r[4 * v4 + 3] += a * w.w;
            }
        }
    }

    const size_t ro = (size_t)n * 102 + (size_t)mod * 51;
#pragma unroll
    for (int v = 0; v < 51; ++v) stv(out, ro + v, isb, r[v]);
}

extern "C" void kernel_launch(void* const* d_in, const int* in_sizes, int n_in,
                              void* d_out, int out_size, void* d_ws, size_t ws_size,
                              hipStream_t stream) {
    const int N = in_sizes[0] / 2;
    const void* obs      = d_in[0];
    const void* p        = d_in[1];
    const void* eps_skip = d_in[2];
    const void* eps_poe  = d_in[3];
    const int*  nbs      = (const int*)d_in[4];
    const int*  nbo      = (const int*)d_in[5];

    int* flag = (int*)d_ws;                 // 64-byte flag region
    u16* gt   = (u16*)d_ws + 32;            // gather table, N*64 bytes

    dim3 blk(256);
    dim3 grdA((N + 255) / 256);
    dim3 grdB((2 * N + 255) / 256);
    hipLaunchKernelGGL(k_detect, dim3(1), dim3(64), 0, stream,
                       (const unsigned int*)obs, flag);
    hipLaunchKernelGGL(k_encode, grdA, blk, 0, stream,
                       obs, d_in[6], d_in[7], d_in[8], d_in[9], d_in[10], d_in[11],
                       flag, gt, N);
    hipLaunchKernelGGL(k_poe_decode, grdB, blk, 0, stream,
                       p, eps_skip, eps_poe, nbs, nbo,
                       d_in[12], d_in[13], d_in[14], d_in[15], d_in[16], d_in[17],
                       flag, gt, (void*)d_out, N);
}